// Round 4
// baseline (717.034 us; speedup 1.0000x reference)
//
#include <hip/hip_runtime.h>

// out = L@(X@W1 + X^2@W2) + X@W1 + b1 + b2
// Y = X@W1 + X^2@W2 (ws), Z = X@W1 + b1 + b2 (node_transform writes Z to out).
// Edges are binned into 128-row buckets (LDS-staged, coalesced writes), then
// one block per bucket accumulates v*Y[col] into a 128x64 LDS accumulator
// (ds_add_f32) and adds it to out. No global atomics on the output.

#define ROWS_PER_BUCKET 128
#define ROW_SHIFT 7
#define NBUCK_MAX 1024
#define CHUNK 4096
#define COL_BITS 17
#define COL_MASK 0x1FFFF

__global__ __launch_bounds__(256) void node_transform(
    const float* __restrict__ X, const float* __restrict__ W1,
    const float* __restrict__ b1, const float* __restrict__ W2,
    const float* __restrict__ b2, float* __restrict__ Y,
    float* __restrict__ Z, int n_nodes)
{
    __shared__ float W1s[64 * 64];
    __shared__ float W2s[64 * 64];
    __shared__ float xs[128][65];
    __shared__ float bs[64];

    const int tid = threadIdx.x;
    const int base = blockIdx.x * 128;

    {
        const float4* w1v = (const float4*)W1;
        const float4* w2v = (const float4*)W2;
        float4* s1 = (float4*)W1s;
        float4* s2 = (float4*)W2s;
#pragma unroll
        for (int i = 0; i < 4; ++i) {
            s1[tid + 256 * i] = w1v[tid + 256 * i];
            s2[tid + 256 * i] = w2v[tid + 256 * i];
        }
    }
    if (tid < 64) bs[tid] = b1[tid] + b2[tid];

    {
#pragma unroll
        for (int i = 0; i < 8; ++i) {
            int idx = (tid + 256 * i) * 4;
            int r = idx >> 6, c = idx & 63;
            if (base + r < n_nodes) {
                float4 v = *(const float4*)(X + (size_t)base * 64 + idx);
                xs[r][c + 0] = v.x; xs[r][c + 1] = v.y;
                xs[r][c + 2] = v.z; xs[r][c + 3] = v.w;
            }
        }
    }
    __syncthreads();

    const int tx = tid & 7;
    const int ty = tid >> 3;

    float acc1[4][8] = {};
    float acc2[4][8] = {};

#pragma unroll 2
    for (int k = 0; k < 64; ++k) {
        float4 wa0 = *(const float4*)(W1s + k * 64 + tx * 8);
        float4 wa1 = *(const float4*)(W1s + k * 64 + tx * 8 + 4);
        float4 wb0 = *(const float4*)(W2s + k * 64 + tx * 8);
        float4 wb1 = *(const float4*)(W2s + k * 64 + tx * 8 + 4);
#pragma unroll
        for (int i = 0; i < 4; ++i) {
            float xv = xs[ty * 4 + i][k];
            float xq = xv * xv;
            acc1[i][0] = fmaf(xv, wa0.x, acc1[i][0]);
            acc1[i][1] = fmaf(xv, wa0.y, acc1[i][1]);
            acc1[i][2] = fmaf(xv, wa0.z, acc1[i][2]);
            acc1[i][3] = fmaf(xv, wa0.w, acc1[i][3]);
            acc1[i][4] = fmaf(xv, wa1.x, acc1[i][4]);
            acc1[i][5] = fmaf(xv, wa1.y, acc1[i][5]);
            acc1[i][6] = fmaf(xv, wa1.z, acc1[i][6]);
            acc1[i][7] = fmaf(xv, wa1.w, acc1[i][7]);
            acc2[i][0] = fmaf(xq, wb0.x, acc2[i][0]);
            acc2[i][1] = fmaf(xq, wb0.y, acc2[i][1]);
            acc2[i][2] = fmaf(xq, wb0.z, acc2[i][2]);
            acc2[i][3] = fmaf(xq, wb0.w, acc2[i][3]);
            acc2[i][4] = fmaf(xq, wb1.x, acc2[i][4]);
            acc2[i][5] = fmaf(xq, wb1.y, acc2[i][5]);
            acc2[i][6] = fmaf(xq, wb1.z, acc2[i][6]);
            acc2[i][7] = fmaf(xq, wb1.w, acc2[i][7]);
        }
    }

    float bv[8];
#pragma unroll
    for (int j = 0; j < 8; ++j) bv[j] = bs[tx * 8 + j];

#pragma unroll
    for (int i = 0; i < 4; ++i) {
        int node = base + ty * 4 + i;
        if (node < n_nodes) {
            float y[8], z[8];
#pragma unroll
            for (int j = 0; j < 8; ++j) {
                y[j] = acc1[i][j] + acc2[i][j];
                z[j] = acc1[i][j] + bv[j];
            }
            float* yp = Y + (size_t)node * 64 + tx * 8;
            float* zp = Z + (size_t)node * 64 + tx * 8;
            *(float4*)(yp)     = make_float4(y[0], y[1], y[2], y[3]);
            *(float4*)(yp + 4) = make_float4(y[4], y[5], y[6], y[7]);
            *(float4*)(zp)     = make_float4(z[0], z[1], z[2], z[3]);
            *(float4*)(zp + 4) = make_float4(z[4], z[5], z[6], z[7]);
        }
    }
}

// ---------------- bucket build ----------------

__global__ __launch_bounds__(256) void zero_counts(int* __restrict__ c, int n) {
    int i = blockIdx.x * 256 + threadIdx.x;
    if (i < n) c[i] = 0;
}

// LDS-privatized histogram of row>>ROW_SHIFT
__global__ __launch_bounds__(256) void bucket_hist(
    const int* __restrict__ rows, int* __restrict__ gcount,
    int n_edges, int nbuck) {
    __shared__ int lc[NBUCK_MAX];
    int tid = threadIdx.x;
    for (int k = tid; k < NBUCK_MAX; k += 256) lc[k] = 0;
    __syncthreads();
    int eb0 = blockIdx.x * CHUNK;
    int cnt = min(CHUNK, n_edges - eb0);
    for (int i = tid; i < cnt; i += 256)
        atomicAdd(&lc[rows[eb0 + i] >> ROW_SHIFT], 1);
    __syncthreads();
    for (int k = tid; k < nbuck; k += 256)
        if (lc[k] > 0) atomicAdd(&gcount[k], lc[k]);
}

// one-block exclusive scan of nbuck (<=1024) counts; init cursor = start
__global__ __launch_bounds__(1024) void scan_buckets(
    const int* __restrict__ gcount, int* __restrict__ bstart,
    int* __restrict__ gcursor, int nb) {
    __shared__ int s[1024];
    int i = threadIdx.x;
    int v = (i < nb) ? gcount[i] : 0;
    s[i] = v;
    __syncthreads();
#pragma unroll
    for (int o = 1; o < 1024; o <<= 1) {
        int t = (i >= o) ? s[i - o] : 0;
        __syncthreads();
        s[i] += t;
        __syncthreads();
    }
    if (i < nb) {
        int excl = s[i] - v;
        bstart[i] = excl;
        gcursor[i] = excl;
    }
}

// LDS-staged binned scatter: local bucket-sort of a 4096-edge chunk, then
// coalesced flush of bucket-sorted runs to global.
__global__ __launch_bounds__(256) void bin_scatter(
    const int* __restrict__ rows, const int* __restrict__ cols,
    const float* __restrict__ vals, int* __restrict__ gcursor,
    int2* __restrict__ packed, int n_edges) {
    __shared__ int lcount[NBUCK_MAX];
    __shared__ int lstart[NBUCK_MAX];
    __shared__ int lcursor[NBUCK_MAX];
    __shared__ int gbase[NBUCK_MAX];
    __shared__ int sx[CHUNK];
    __shared__ int sy[CHUNK];
    __shared__ unsigned short sbk[CHUNK];

    int tid = threadIdx.x;
    int eb0 = blockIdx.x * CHUNK;
    int cnt = min(CHUNK, n_edges - eb0);

    for (int k = tid; k < NBUCK_MAX; k += 256) lcount[k] = 0;
    __syncthreads();

    // pass 1: local histogram
    for (int i = tid; i < cnt; i += 256)
        atomicAdd(&lcount[rows[eb0 + i] >> ROW_SHIFT], 1);
    __syncthreads();

    // blocked exclusive scan of lcount[0..1023]; thread t owns 4t..4t+3
    int c0 = lcount[tid * 4 + 0], c1 = lcount[tid * 4 + 1];
    int c2 = lcount[tid * 4 + 2], c3 = lcount[tid * 4 + 3];
    int psum = c0 + c1 + c2 + c3;
    sx[tid] = psum;          // reuse sx[0..255] as scan partials
    __syncthreads();
#pragma unroll
    for (int o = 1; o < 256; o <<= 1) {
        int t = (tid >= o) ? sx[tid - o] : 0;
        __syncthreads();
        sx[tid] += t;
        __syncthreads();
    }
    int base0 = sx[tid] - psum;   // exclusive base for this thread's 4
    __syncthreads();              // done with sx as scan scratch
    lstart[tid * 4 + 0] = base0;
    lstart[tid * 4 + 1] = base0 + c0;
    lstart[tid * 4 + 2] = base0 + c0 + c1;
    lstart[tid * 4 + 3] = base0 + c0 + c1 + c2;
    __syncthreads();

    // reserve global space, init local cursors
    for (int k = tid; k < NBUCK_MAX; k += 256) {
        lcursor[k] = lstart[k];
        if (lcount[k] > 0) gbase[k] = atomicAdd(&gcursor[k], lcount[k]);
    }
    __syncthreads();

    // pass 2: place edges bucket-sorted in LDS
    for (int i = tid; i < cnt; i += 256) {
        int r = rows[eb0 + i];
        int b = r >> ROW_SHIFT;
        int p = atomicAdd(&lcursor[b], 1);
        sx[p] = ((r & (ROWS_PER_BUCKET - 1)) << COL_BITS) | cols[eb0 + i];
        sy[p] = __float_as_int(vals[eb0 + i]);
        sbk[p] = (unsigned short)b;
    }
    __syncthreads();

    // flush: consecutive slots -> consecutive global dests within runs
    for (int i = tid; i < cnt; i += 256) {
        int b = sbk[i];
        int dest = gbase[b] + (i - lstart[b]);
        packed[dest] = make_int2(sx[i], sy[i]);
    }
}

// one block per bucket; 128x64 LDS accumulator; lane = feature
__global__ __launch_bounds__(256) void bucket_gather(
    const int* __restrict__ bstart, const int* __restrict__ bend,
    const int2* __restrict__ packed, const float* __restrict__ Y,
    float* __restrict__ out, int n_nodes) {
    __shared__ float accum[ROWS_PER_BUCKET * 64];   // 32 KB
    int tid = threadIdx.x;
    int wave = tid >> 6;
    int lane = tid & 63;
    int b = blockIdx.x;

    for (int i = tid; i < ROWS_PER_BUCKET * 64; i += 256) accum[i] = 0.f;
    __syncthreads();

    int s = bstart[b];
    int e = bend[b];
    for (int base = s + wave * 64; base < e; base += 256) {
        int cnt = min(64, e - base);
        int px = 0, py = 0;
        if (lane < cnt) {
            int2 a = packed[base + lane];
            px = a.x; py = a.y;
        }
        int j = 0;
        for (; j + 4 <= cnt; j += 4) {
            int x0 = __shfl(px, j),     x1 = __shfl(px, j + 1);
            int x2 = __shfl(px, j + 2), x3 = __shfl(px, j + 3);
            int y0 = __shfl(py, j),     y1 = __shfl(py, j + 1);
            int y2 = __shfl(py, j + 2), y3 = __shfl(py, j + 3);
            float f0 = Y[(size_t)(x0 & COL_MASK) * 64 + lane];
            float f1 = Y[(size_t)(x1 & COL_MASK) * 64 + lane];
            float f2 = Y[(size_t)(x2 & COL_MASK) * 64 + lane];
            float f3 = Y[(size_t)(x3 & COL_MASK) * 64 + lane];
            atomicAdd(&accum[(x0 >> COL_BITS) * 64 + lane], __int_as_float(y0) * f0);
            atomicAdd(&accum[(x1 >> COL_BITS) * 64 + lane], __int_as_float(y1) * f1);
            atomicAdd(&accum[(x2 >> COL_BITS) * 64 + lane], __int_as_float(y2) * f2);
            atomicAdd(&accum[(x3 >> COL_BITS) * 64 + lane], __int_as_float(y3) * f3);
        }
        for (; j < cnt; ++j) {
            int x0 = __shfl(px, j);
            int y0 = __shfl(py, j);
            float f0 = Y[(size_t)(x0 & COL_MASK) * 64 + lane];
            atomicAdd(&accum[(x0 >> COL_BITS) * 64 + lane], __int_as_float(y0) * f0);
        }
    }
    __syncthreads();

    int nb0 = b * ROWS_PER_BUCKET;
    for (int i = tid; i < ROWS_PER_BUCKET * 64; i += 256) {
        int node = nb0 + (i >> 6);
        if (node < n_nodes) out[(size_t)node * 64 + (i & 63)] += accum[i];
    }
}

// ---------------- fallback (atomic path) ----------------

__global__ __launch_bounds__(256) void edge_scatter(
    const int* __restrict__ rows, const int* __restrict__ cols,
    const float* __restrict__ vals, const float* __restrict__ Y,
    float* __restrict__ out, int n_edges)
{
    int t = blockIdx.x * 256 + threadIdx.x;
    int e = t >> 4;
    int f = (t & 15) << 2;
    if (e >= n_edges) return;
    int r = rows[e];
    int c = cols[e];
    float v = vals[e];
    float4 y = *(const float4*)(Y + (size_t)c * 64 + f);
    float* o = out + (size_t)r * 64 + f;
    atomicAdd(o + 0, v * y.x);
    atomicAdd(o + 1, v * y.y);
    atomicAdd(o + 2, v * y.z);
    atomicAdd(o + 3, v * y.w);
}

extern "C" void kernel_launch(void* const* d_in, const int* in_sizes, int n_in,
                              void* d_out, int out_size, void* d_ws, size_t ws_size,
                              hipStream_t stream) {
    const int*   rows = (const int*)d_in[0];
    const int*   cols = (const int*)d_in[1];
    const float* vals = (const float*)d_in[2];
    const float* X    = (const float*)d_in[3];
    const float* W1   = (const float*)d_in[4];
    const float* b1   = (const float*)d_in[5];
    const float* W2   = (const float*)d_in[6];
    const float* b2   = (const float*)d_in[7];
    float* out = (float*)d_out;

    const int n_edges = in_sizes[0];
    const int n_nodes = in_sizes[3] / 64;
    const int nbuck = (n_nodes + ROWS_PER_BUCKET - 1) / ROWS_PER_BUCKET;

    char* ws = (char*)d_ws;
    size_t o_Y      = 0;
    size_t o_gcount = o_Y + (size_t)n_nodes * 64 * 4;
    size_t o_bstart = o_gcount + NBUCK_MAX * 4;
    size_t o_gcurs  = o_bstart + NBUCK_MAX * 4;
    size_t o_packed = o_gcurs + NBUCK_MAX * 4;
    size_t need     = o_packed + (size_t)n_edges * 8;

    float* Y = (float*)(ws + o_Y);

    int nblocks = (n_nodes + 127) / 128;
    node_transform<<<nblocks, 256, 0, stream>>>(X, W1, b1, W2, b2, Y, out, n_nodes);

    if (ws_size >= need && nbuck <= NBUCK_MAX && n_nodes <= (1 << COL_BITS)) {
        int*  gcount = (int*)(ws + o_gcount);
        int*  bstart = (int*)(ws + o_bstart);
        int*  gcursor= (int*)(ws + o_gcurs);
        int2* packed = (int2*)(ws + o_packed);

        int eb = (n_edges + CHUNK - 1) / CHUNK;

        zero_counts<<<(nbuck + 255) / 256, 256, 0, stream>>>(gcount, nbuck);
        bucket_hist<<<eb, 256, 0, stream>>>(rows, gcount, n_edges, nbuck);
        scan_buckets<<<1, 1024, 0, stream>>>(gcount, bstart, gcursor, nbuck);
        bin_scatter<<<eb, 256, 0, stream>>>(rows, cols, vals, gcursor, packed, n_edges);
        bucket_gather<<<nbuck, 256, 0, stream>>>(bstart, gcursor, packed, Y, out, n_nodes);
    } else {
        long long threads = (long long)n_edges * 16;
        int eblocks = (int)((threads + 255) / 256);
        edge_scatter<<<eblocks, 256, 0, stream>>>(rows, cols, vals, Y, out, n_edges);
    }
}

// Round 5
// 238.118 us; speedup vs baseline: 3.0113x; 3.0113x over previous
//
#include <hip/hip_runtime.h>

// out = L@(X@W1 + X^2@W2) + X@W1 + b1 + b2
// Y = X@W1 + X^2@W2 (ws), Z = X@W1 + b1 + b2 (node_transform writes Z to out).
// Pipeline: bucket_hist/scan -> bin_scatter (edges binned to 128-row buckets,
// LDS-staged coalesced writes) -> bucket_gather_sorted (per-bucket in-LDS
// counting sort by row + REGISTER-accumulated gather, one coalesced out+= per
// row). No global output atomics, no LDS atomics in the gather hot loop.

#define ROWS_PER_BUCKET 128
#define ROW_SHIFT 7
#define NBUCK_MAX 1024
#define CHUNK 4096          // edges per bin_scatter block
#define MAXB 2048           // max bucket-chunk held in LDS by gather
#define COL_BITS 17
#define COL_MASK 0x1FFFF

__global__ __launch_bounds__(256) void node_transform(
    const float* __restrict__ X, const float* __restrict__ W1,
    const float* __restrict__ b1, const float* __restrict__ W2,
    const float* __restrict__ b2, float* __restrict__ Y,
    float* __restrict__ Z, int n_nodes)
{
    __shared__ float W1s[64 * 64];
    __shared__ float W2s[64 * 64];
    __shared__ float xs[128][65];
    __shared__ float bs[64];

    const int tid = threadIdx.x;
    const int base = blockIdx.x * 128;

    {
        const float4* w1v = (const float4*)W1;
        const float4* w2v = (const float4*)W2;
        float4* s1 = (float4*)W1s;
        float4* s2 = (float4*)W2s;
#pragma unroll
        for (int i = 0; i < 4; ++i) {
            s1[tid + 256 * i] = w1v[tid + 256 * i];
            s2[tid + 256 * i] = w2v[tid + 256 * i];
        }
    }
    if (tid < 64) bs[tid] = b1[tid] + b2[tid];

    {
#pragma unroll
        for (int i = 0; i < 8; ++i) {
            int idx = (tid + 256 * i) * 4;
            int r = idx >> 6, c = idx & 63;
            if (base + r < n_nodes) {
                float4 v = *(const float4*)(X + (size_t)base * 64 + idx);
                xs[r][c + 0] = v.x; xs[r][c + 1] = v.y;
                xs[r][c + 2] = v.z; xs[r][c + 3] = v.w;
            }
        }
    }
    __syncthreads();

    const int tx = tid & 7;
    const int ty = tid >> 3;

    float acc1[4][8] = {};
    float acc2[4][8] = {};

#pragma unroll 2
    for (int k = 0; k < 64; ++k) {
        float4 wa0 = *(const float4*)(W1s + k * 64 + tx * 8);
        float4 wa1 = *(const float4*)(W1s + k * 64 + tx * 8 + 4);
        float4 wb0 = *(const float4*)(W2s + k * 64 + tx * 8);
        float4 wb1 = *(const float4*)(W2s + k * 64 + tx * 8 + 4);
#pragma unroll
        for (int i = 0; i < 4; ++i) {
            float xv = xs[ty * 4 + i][k];
            float xq = xv * xv;
            acc1[i][0] = fmaf(xv, wa0.x, acc1[i][0]);
            acc1[i][1] = fmaf(xv, wa0.y, acc1[i][1]);
            acc1[i][2] = fmaf(xv, wa0.z, acc1[i][2]);
            acc1[i][3] = fmaf(xv, wa0.w, acc1[i][3]);
            acc1[i][4] = fmaf(xv, wa1.x, acc1[i][4]);
            acc1[i][5] = fmaf(xv, wa1.y, acc1[i][5]);
            acc1[i][6] = fmaf(xv, wa1.z, acc1[i][6]);
            acc1[i][7] = fmaf(xv, wa1.w, acc1[i][7]);
            acc2[i][0] = fmaf(xq, wb0.x, acc2[i][0]);
            acc2[i][1] = fmaf(xq, wb0.y, acc2[i][1]);
            acc2[i][2] = fmaf(xq, wb0.z, acc2[i][2]);
            acc2[i][3] = fmaf(xq, wb0.w, acc2[i][3]);
            acc2[i][4] = fmaf(xq, wb1.x, acc2[i][4]);
            acc2[i][5] = fmaf(xq, wb1.y, acc2[i][5]);
            acc2[i][6] = fmaf(xq, wb1.z, acc2[i][6]);
            acc2[i][7] = fmaf(xq, wb1.w, acc2[i][7]);
        }
    }

    float bv[8];
#pragma unroll
    for (int j = 0; j < 8; ++j) bv[j] = bs[tx * 8 + j];

#pragma unroll
    for (int i = 0; i < 4; ++i) {
        int node = base + ty * 4 + i;
        if (node < n_nodes) {
            float y[8], z[8];
#pragma unroll
            for (int j = 0; j < 8; ++j) {
                y[j] = acc1[i][j] + acc2[i][j];
                z[j] = acc1[i][j] + bv[j];
            }
            float* yp = Y + (size_t)node * 64 + tx * 8;
            float* zp = Z + (size_t)node * 64 + tx * 8;
            *(float4*)(yp)     = make_float4(y[0], y[1], y[2], y[3]);
            *(float4*)(yp + 4) = make_float4(y[4], y[5], y[6], y[7]);
            *(float4*)(zp)     = make_float4(z[0], z[1], z[2], z[3]);
            *(float4*)(zp + 4) = make_float4(z[4], z[5], z[6], z[7]);
        }
    }
}

// ---------------- bucket build ----------------

__global__ __launch_bounds__(256) void zero_counts(int* __restrict__ c, int n) {
    int i = blockIdx.x * 256 + threadIdx.x;
    if (i < n) c[i] = 0;
}

__global__ __launch_bounds__(256) void bucket_hist(
    const int* __restrict__ rows, int* __restrict__ gcount,
    int n_edges, int nbuck) {
    __shared__ int lc[NBUCK_MAX];
    int tid = threadIdx.x;
    for (int k = tid; k < NBUCK_MAX; k += 256) lc[k] = 0;
    __syncthreads();
    int eb0 = blockIdx.x * CHUNK;
    int cnt = min(CHUNK, n_edges - eb0);
    for (int i = tid; i < cnt; i += 256)
        atomicAdd(&lc[rows[eb0 + i] >> ROW_SHIFT], 1);
    __syncthreads();
    for (int k = tid; k < nbuck; k += 256)
        if (lc[k] > 0) atomicAdd(&gcount[k], lc[k]);
}

__global__ __launch_bounds__(1024) void scan_buckets(
    const int* __restrict__ gcount, int* __restrict__ bstart,
    int* __restrict__ gcursor, int nb) {
    __shared__ int s[1024];
    int i = threadIdx.x;
    int v = (i < nb) ? gcount[i] : 0;
    s[i] = v;
    __syncthreads();
#pragma unroll
    for (int o = 1; o < 1024; o <<= 1) {
        int t = (i >= o) ? s[i - o] : 0;
        __syncthreads();
        s[i] += t;
        __syncthreads();
    }
    if (i < nb) {
        int excl = s[i] - v;
        bstart[i] = excl;
        gcursor[i] = excl;
    }
}

// LDS-staged binned scatter: local bucket-sort of a 4096-edge chunk, then
// coalesced flush of bucket-sorted runs to global.
__global__ __launch_bounds__(256) void bin_scatter(
    const int* __restrict__ rows, const int* __restrict__ cols,
    const float* __restrict__ vals, int* __restrict__ gcursor,
    int2* __restrict__ packed, int n_edges) {
    __shared__ int lcount[NBUCK_MAX];
    __shared__ int lstart[NBUCK_MAX];
    __shared__ int lcursor[NBUCK_MAX];
    __shared__ int gbase[NBUCK_MAX];
    __shared__ int sx[CHUNK];
    __shared__ int sy[CHUNK];
    __shared__ unsigned short sbk[CHUNK];

    int tid = threadIdx.x;
    int eb0 = blockIdx.x * CHUNK;
    int cnt = min(CHUNK, n_edges - eb0);

    for (int k = tid; k < NBUCK_MAX; k += 256) lcount[k] = 0;
    __syncthreads();

    for (int i = tid; i < cnt; i += 256)
        atomicAdd(&lcount[rows[eb0 + i] >> ROW_SHIFT], 1);
    __syncthreads();

    int c0 = lcount[tid * 4 + 0], c1 = lcount[tid * 4 + 1];
    int c2 = lcount[tid * 4 + 2], c3 = lcount[tid * 4 + 3];
    int psum = c0 + c1 + c2 + c3;
    sx[tid] = psum;
    __syncthreads();
#pragma unroll
    for (int o = 1; o < 256; o <<= 1) {
        int t = (tid >= o) ? sx[tid - o] : 0;
        __syncthreads();
        sx[tid] += t;
        __syncthreads();
    }
    int base0 = sx[tid] - psum;
    __syncthreads();
    lstart[tid * 4 + 0] = base0;
    lstart[tid * 4 + 1] = base0 + c0;
    lstart[tid * 4 + 2] = base0 + c0 + c1;
    lstart[tid * 4 + 3] = base0 + c0 + c1 + c2;
    __syncthreads();

    for (int k = tid; k < NBUCK_MAX; k += 256) {
        lcursor[k] = lstart[k];
        if (lcount[k] > 0) gbase[k] = atomicAdd(&gcursor[k], lcount[k]);
    }
    __syncthreads();

    for (int i = tid; i < cnt; i += 256) {
        int r = rows[eb0 + i];
        int b = r >> ROW_SHIFT;
        int p = atomicAdd(&lcursor[b], 1);
        sx[p] = ((r & (ROWS_PER_BUCKET - 1)) << COL_BITS) | cols[eb0 + i];
        sy[p] = __float_as_int(vals[eb0 + i]);
        sbk[p] = (unsigned short)b;
    }
    __syncthreads();

    for (int i = tid; i < cnt; i += 256) {
        int b = sbk[i];
        int dest = gbase[b] + (i - lstart[b]);
        packed[dest] = make_int2(sx[i], sy[i]);
    }
}

// one block per bucket: in-LDS counting sort (by local row) of up to MAXB
// edges, then register-accumulated gather: wave w handles rows w*32..w*32+31,
// lane = feature, 8-wide unrolled independent Y loads, coalesced out+=.
__global__ __launch_bounds__(256) void bucket_gather_sorted(
    const int* __restrict__ bstart, const int* __restrict__ bend,
    const int2* __restrict__ packed, const float* __restrict__ Y,
    float* __restrict__ out, int n_nodes) {
    __shared__ int2 sxy[MAXB];                     // 16 KB
    __shared__ unsigned short dsti[MAXB];          // 4 KB
    __shared__ int hist[ROWS_PER_BUCKET];
    __shared__ int chs[ROWS_PER_BUCKET];
    __shared__ int chc[ROWS_PER_BUCKET];

    int tid = threadIdx.x;
    int wave = tid >> 6;
    int lane = tid & 63;
    int b = blockIdx.x;
    int s = bstart[b];
    int e = bend[b];
    int row0 = b * ROWS_PER_BUCKET;

    for (int cb = s; cb < e; cb += MAXB) {
        int cnt = min(MAXB, e - cb);

        if (tid < ROWS_PER_BUCKET) hist[tid] = 0;
        __syncthreads();

        // load chunk to LDS + local row histogram
        for (int i = tid; i < cnt; i += 256) {
            int2 a = packed[cb + i];
            sxy[i] = a;
            atomicAdd(&hist[a.x >> COL_BITS], 1);
        }
        __syncthreads();

        // exclusive scan of hist[0..127] -> chs; chc = placement cursor
        if (tid < ROWS_PER_BUCKET) chs[tid] = hist[tid];
        __syncthreads();
#pragma unroll
        for (int o = 1; o < ROWS_PER_BUCKET; o <<= 1) {
            int t = 0;
            if (tid < ROWS_PER_BUCKET && tid >= o) t = chs[tid - o];
            __syncthreads();
            if (tid < ROWS_PER_BUCKET) chs[tid] += t;
            __syncthreads();
        }
        if (tid < ROWS_PER_BUCKET) {
            int excl = chs[tid] - hist[tid];
            chs[tid] = excl;
            chc[tid] = excl;
        }
        __syncthreads();

        // place indices sorted by row
        for (int i = tid; i < cnt; i += 256) {
            int r = sxy[i].x >> COL_BITS;
            int p = atomicAdd(&chc[r], 1);
            dsti[p] = (unsigned short)i;
        }
        __syncthreads();

        // register-accumulated gather; wave-broadcast LDS reads
        for (int rr = 0; rr < 32; ++rr) {
            int r = wave * 32 + rr;
            int rc = hist[r];
            if (rc == 0) continue;
            int node = row0 + r;
            if (node >= n_nodes) continue;
            int rs = chs[r];
            float acc = 0.f;
            int j = 0;
            for (; j + 8 <= rc; j += 8) {
                int i0 = dsti[rs + j + 0], i1 = dsti[rs + j + 1];
                int i2 = dsti[rs + j + 2], i3 = dsti[rs + j + 3];
                int i4 = dsti[rs + j + 4], i5 = dsti[rs + j + 5];
                int i6 = dsti[rs + j + 6], i7 = dsti[rs + j + 7];
                int2 a0 = sxy[i0], a1 = sxy[i1], a2 = sxy[i2], a3 = sxy[i3];
                int2 a4 = sxy[i4], a5 = sxy[i5], a6 = sxy[i6], a7 = sxy[i7];
                float f0 = Y[(size_t)(a0.x & COL_MASK) * 64 + lane];
                float f1 = Y[(size_t)(a1.x & COL_MASK) * 64 + lane];
                float f2 = Y[(size_t)(a2.x & COL_MASK) * 64 + lane];
                float f3 = Y[(size_t)(a3.x & COL_MASK) * 64 + lane];
                float f4 = Y[(size_t)(a4.x & COL_MASK) * 64 + lane];
                float f5 = Y[(size_t)(a5.x & COL_MASK) * 64 + lane];
                float f6 = Y[(size_t)(a6.x & COL_MASK) * 64 + lane];
                float f7 = Y[(size_t)(a7.x & COL_MASK) * 64 + lane];
                acc = fmaf(__int_as_float(a0.y), f0, acc);
                acc = fmaf(__int_as_float(a1.y), f1, acc);
                acc = fmaf(__int_as_float(a2.y), f2, acc);
                acc = fmaf(__int_as_float(a3.y), f3, acc);
                acc = fmaf(__int_as_float(a4.y), f4, acc);
                acc = fmaf(__int_as_float(a5.y), f5, acc);
                acc = fmaf(__int_as_float(a6.y), f6, acc);
                acc = fmaf(__int_as_float(a7.y), f7, acc);
            }
            for (; j + 4 <= rc; j += 4) {
                int i0 = dsti[rs + j + 0], i1 = dsti[rs + j + 1];
                int i2 = dsti[rs + j + 2], i3 = dsti[rs + j + 3];
                int2 a0 = sxy[i0], a1 = sxy[i1], a2 = sxy[i2], a3 = sxy[i3];
                float f0 = Y[(size_t)(a0.x & COL_MASK) * 64 + lane];
                float f1 = Y[(size_t)(a1.x & COL_MASK) * 64 + lane];
                float f2 = Y[(size_t)(a2.x & COL_MASK) * 64 + lane];
                float f3 = Y[(size_t)(a3.x & COL_MASK) * 64 + lane];
                acc = fmaf(__int_as_float(a0.y), f0, acc);
                acc = fmaf(__int_as_float(a1.y), f1, acc);
                acc = fmaf(__int_as_float(a2.y), f2, acc);
                acc = fmaf(__int_as_float(a3.y), f3, acc);
            }
            for (; j < rc; ++j) {
                int i0 = dsti[rs + j];
                int2 a0 = sxy[i0];
                acc = fmaf(__int_as_float(a0.y),
                           Y[(size_t)(a0.x & COL_MASK) * 64 + lane], acc);
            }
            out[(size_t)node * 64 + lane] += acc;   // out holds Z
        }
        __syncthreads();
    }
}

// ---------------- fallback (atomic path) ----------------

__global__ __launch_bounds__(256) void edge_scatter(
    const int* __restrict__ rows, const int* __restrict__ cols,
    const float* __restrict__ vals, const float* __restrict__ Y,
    float* __restrict__ out, int n_edges)
{
    int t = blockIdx.x * 256 + threadIdx.x;
    int e = t >> 4;
    int f = (t & 15) << 2;
    if (e >= n_edges) return;
    int r = rows[e];
    int c = cols[e];
    float v = vals[e];
    float4 y = *(const float4*)(Y + (size_t)c * 64 + f);
    float* o = out + (size_t)r * 64 + f;
    atomicAdd(o + 0, v * y.x);
    atomicAdd(o + 1, v * y.y);
    atomicAdd(o + 2, v * y.z);
    atomicAdd(o + 3, v * y.w);
}

extern "C" void kernel_launch(void* const* d_in, const int* in_sizes, int n_in,
                              void* d_out, int out_size, void* d_ws, size_t ws_size,
                              hipStream_t stream) {
    const int*   rows = (const int*)d_in[0];
    const int*   cols = (const int*)d_in[1];
    const float* vals = (const float*)d_in[2];
    const float* X    = (const float*)d_in[3];
    const float* W1   = (const float*)d_in[4];
    const float* b1   = (const float*)d_in[5];
    const float* W2   = (const float*)d_in[6];
    const float* b2   = (const float*)d_in[7];
    float* out = (float*)d_out;

    const int n_edges = in_sizes[0];
    const int n_nodes = in_sizes[3] / 64;
    const int nbuck = (n_nodes + ROWS_PER_BUCKET - 1) / ROWS_PER_BUCKET;

    char* ws = (char*)d_ws;
    size_t o_Y      = 0;
    size_t o_gcount = o_Y + (size_t)n_nodes * 64 * 4;
    size_t o_bstart = o_gcount + NBUCK_MAX * 4;
    size_t o_gcurs  = o_bstart + NBUCK_MAX * 4;
    size_t o_packed = o_gcurs + NBUCK_MAX * 4;
    size_t need     = o_packed + (size_t)n_edges * 8;

    float* Y = (float*)(ws + o_Y);

    int nblocks = (n_nodes + 127) / 128;
    node_transform<<<nblocks, 256, 0, stream>>>(X, W1, b1, W2, b2, Y, out, n_nodes);

    if (ws_size >= need && nbuck <= NBUCK_MAX && n_nodes <= (1 << COL_BITS)) {
        int*  gcount = (int*)(ws + o_gcount);
        int*  bstart = (int*)(ws + o_bstart);
        int*  gcursor= (int*)(ws + o_gcurs);
        int2* packed = (int2*)(ws + o_packed);

        int eb = (n_edges + CHUNK - 1) / CHUNK;

        zero_counts<<<(nbuck + 255) / 256, 256, 0, stream>>>(gcount, nbuck);
        bucket_hist<<<eb, 256, 0, stream>>>(rows, gcount, n_edges, nbuck);
        scan_buckets<<<1, 1024, 0, stream>>>(gcount, bstart, gcursor, nbuck);
        bin_scatter<<<eb, 256, 0, stream>>>(rows, cols, vals, gcursor, packed, n_edges);
        bucket_gather_sorted<<<nbuck, 256, 0, stream>>>(bstart, gcursor, packed, Y, out, n_nodes);
    } else {
        long long threads = (long long)n_edges * 16;
        int eblocks = (int)((threads + 255) / 256);
        edge_scatter<<<eblocks, 256, 0, stream>>>(rows, cols, vals, Y, out, n_edges);
    }
}

// Round 6
// 228.980 us; speedup vs baseline: 3.1314x; 1.0399x over previous
//
#include <hip/hip_runtime.h>

// out = L@(X@W1 + X^2@W2) + X@W1 + b1 + b2
// Y = X@W1 + X^2@W2 (ws), Z = X@W1 + b1 + b2 (node_transform writes Z to out).
// Pipeline: bucket_hist/scan -> bin_scatter (edges binned to 128-row buckets,
// LDS-staged coalesced writes) -> bucket_gather_split (2 blocks per bucket,
// 32 features each: in-LDS counting sort by row + register-accumulated
// gather, coalesced out+=). No global output atomics.

#define ROWS_PER_BUCKET 128
#define ROW_SHIFT 7
#define NBUCK_PAD 784        // 196*4, covers nbuck=782
#define SCAN_T 196
#define CHUNK 2048           // edges per bin_scatter/hist block
#define MAXB 2048            // max bucket-chunk held in LDS by gather
#define COL_BITS 17
#define COL_MASK 0x1FFFF

__global__ __launch_bounds__(256) void node_transform(
    const float* __restrict__ X, const float* __restrict__ W1,
    const float* __restrict__ b1, const float* __restrict__ W2,
    const float* __restrict__ b2, float* __restrict__ Y,
    float* __restrict__ Z, int n_nodes)
{
    __shared__ float W1s[64 * 64];
    __shared__ float W2s[64 * 64];
    __shared__ float xs[128][65];
    __shared__ float bs[64];

    const int tid = threadIdx.x;
    const int base = blockIdx.x * 128;

    {
        const float4* w1v = (const float4*)W1;
        const float4* w2v = (const float4*)W2;
        float4* s1 = (float4*)W1s;
        float4* s2 = (float4*)W2s;
#pragma unroll
        for (int i = 0; i < 4; ++i) {
            s1[tid + 256 * i] = w1v[tid + 256 * i];
            s2[tid + 256 * i] = w2v[tid + 256 * i];
        }
    }
    if (tid < 64) bs[tid] = b1[tid] + b2[tid];

    {
#pragma unroll
        for (int i = 0; i < 8; ++i) {
            int idx = (tid + 256 * i) * 4;
            int r = idx >> 6, c = idx & 63;
            if (base + r < n_nodes) {
                float4 v = *(const float4*)(X + (size_t)base * 64 + idx);
                xs[r][c + 0] = v.x; xs[r][c + 1] = v.y;
                xs[r][c + 2] = v.z; xs[r][c + 3] = v.w;
            }
        }
    }
    __syncthreads();

    const int tx = tid & 7;
    const int ty = tid >> 3;

    float acc1[4][8] = {};
    float acc2[4][8] = {};

#pragma unroll 2
    for (int k = 0; k < 64; ++k) {
        float4 wa0 = *(const float4*)(W1s + k * 64 + tx * 8);
        float4 wa1 = *(const float4*)(W1s + k * 64 + tx * 8 + 4);
        float4 wb0 = *(const float4*)(W2s + k * 64 + tx * 8);
        float4 wb1 = *(const float4*)(W2s + k * 64 + tx * 8 + 4);
#pragma unroll
        for (int i = 0; i < 4; ++i) {
            float xv = xs[ty * 4 + i][k];
            float xq = xv * xv;
            acc1[i][0] = fmaf(xv, wa0.x, acc1[i][0]);
            acc1[i][1] = fmaf(xv, wa0.y, acc1[i][1]);
            acc1[i][2] = fmaf(xv, wa0.z, acc1[i][2]);
            acc1[i][3] = fmaf(xv, wa0.w, acc1[i][3]);
            acc1[i][4] = fmaf(xv, wa1.x, acc1[i][4]);
            acc1[i][5] = fmaf(xv, wa1.y, acc1[i][5]);
            acc1[i][6] = fmaf(xv, wa1.z, acc1[i][6]);
            acc1[i][7] = fmaf(xv, wa1.w, acc1[i][7]);
            acc2[i][0] = fmaf(xq, wb0.x, acc2[i][0]);
            acc2[i][1] = fmaf(xq, wb0.y, acc2[i][1]);
            acc2[i][2] = fmaf(xq, wb0.z, acc2[i][2]);
            acc2[i][3] = fmaf(xq, wb0.w, acc2[i][3]);
            acc2[i][4] = fmaf(xq, wb1.x, acc2[i][4]);
            acc2[i][5] = fmaf(xq, wb1.y, acc2[i][5]);
            acc2[i][6] = fmaf(xq, wb1.z, acc2[i][6]);
            acc2[i][7] = fmaf(xq, wb1.w, acc2[i][7]);
        }
    }

    float bv[8];
#pragma unroll
    for (int j = 0; j < 8; ++j) bv[j] = bs[tx * 8 + j];

#pragma unroll
    for (int i = 0; i < 4; ++i) {
        int node = base + ty * 4 + i;
        if (node < n_nodes) {
            float y[8], z[8];
#pragma unroll
            for (int j = 0; j < 8; ++j) {
                y[j] = acc1[i][j] + acc2[i][j];
                z[j] = acc1[i][j] + bv[j];
            }
            float* yp = Y + (size_t)node * 64 + tx * 8;
            float* zp = Z + (size_t)node * 64 + tx * 8;
            *(float4*)(yp)     = make_float4(y[0], y[1], y[2], y[3]);
            *(float4*)(yp + 4) = make_float4(y[4], y[5], y[6], y[7]);
            *(float4*)(zp)     = make_float4(z[0], z[1], z[2], z[3]);
            *(float4*)(zp + 4) = make_float4(z[4], z[5], z[6], z[7]);
        }
    }
}

// ---------------- bucket build ----------------

__global__ __launch_bounds__(256) void zero_counts(int* __restrict__ c, int n) {
    int i = blockIdx.x * 256 + threadIdx.x;
    if (i < n) c[i] = 0;
}

__global__ __launch_bounds__(256) void bucket_hist(
    const int* __restrict__ rows, int* __restrict__ gcount,
    int n_edges, int nbuck) {
    __shared__ int lc[NBUCK_PAD];
    int tid = threadIdx.x;
    for (int k = tid; k < NBUCK_PAD; k += 256) lc[k] = 0;
    __syncthreads();
    int eb0 = blockIdx.x * CHUNK;
    int cnt = min(CHUNK, n_edges - eb0);
    for (int i = tid; i < cnt; i += 256)
        atomicAdd(&lc[rows[eb0 + i] >> ROW_SHIFT], 1);
    __syncthreads();
    for (int k = tid; k < nbuck; k += 256)
        if (lc[k] > 0) atomicAdd(&gcount[k], lc[k]);
}

__global__ __launch_bounds__(1024) void scan_buckets(
    const int* __restrict__ gcount, int* __restrict__ bstart,
    int* __restrict__ gcursor, int nb) {
    __shared__ int s[1024];
    int i = threadIdx.x;
    int v = (i < nb) ? gcount[i] : 0;
    s[i] = v;
    __syncthreads();
#pragma unroll
    for (int o = 1; o < 1024; o <<= 1) {
        int t = (i >= o) ? s[i - o] : 0;
        __syncthreads();
        s[i] += t;
        __syncthreads();
    }
    if (i < nb) {
        int excl = s[i] - v;
        bstart[i] = excl;
        gcursor[i] = excl;
    }
}

// LDS-staged binned scatter: local bucket-sort of a CHUNK-edge run, then
// coalesced flush of bucket-sorted runs to global. LDS ~33 KB.
__global__ __launch_bounds__(256) void bin_scatter(
    const int* __restrict__ rows, const int* __restrict__ cols,
    const float* __restrict__ vals, int* __restrict__ gcursor,
    int2* __restrict__ packed, int n_edges) {
    __shared__ int lcount[NBUCK_PAD];
    __shared__ int lstart[NBUCK_PAD];
    __shared__ int lcursor[NBUCK_PAD];
    __shared__ int gbase[NBUCK_PAD];
    __shared__ int sx[CHUNK];
    __shared__ int sy[CHUNK];
    __shared__ unsigned short sbk[CHUNK];

    int tid = threadIdx.x;
    int eb0 = blockIdx.x * CHUNK;
    int cnt = min(CHUNK, n_edges - eb0);

    for (int k = tid; k < NBUCK_PAD; k += 256) lcount[k] = 0;
    __syncthreads();

    for (int i = tid; i < cnt; i += 256)
        atomicAdd(&lcount[rows[eb0 + i] >> ROW_SHIFT], 1);
    __syncthreads();

    // exclusive scan of lcount[0..NBUCK_PAD): thread t<SCAN_T owns 4t..4t+3
    int c0 = 0, c1 = 0, c2 = 0, c3 = 0, psum = 0;
    if (tid < SCAN_T) {
        c0 = lcount[tid * 4 + 0]; c1 = lcount[tid * 4 + 1];
        c2 = lcount[tid * 4 + 2]; c3 = lcount[tid * 4 + 3];
        psum = c0 + c1 + c2 + c3;
    }
    sx[tid] = psum;
    __syncthreads();
#pragma unroll
    for (int o = 1; o < 256; o <<= 1) {
        int t = (tid >= o) ? sx[tid - o] : 0;
        __syncthreads();
        sx[tid] += t;
        __syncthreads();
    }
    int base0 = sx[tid] - psum;
    __syncthreads();
    if (tid < SCAN_T) {
        lstart[tid * 4 + 0] = base0;
        lstart[tid * 4 + 1] = base0 + c0;
        lstart[tid * 4 + 2] = base0 + c0 + c1;
        lstart[tid * 4 + 3] = base0 + c0 + c1 + c2;
    }
    __syncthreads();

    for (int k = tid; k < NBUCK_PAD; k += 256) {
        lcursor[k] = lstart[k];
        if (lcount[k] > 0) gbase[k] = atomicAdd(&gcursor[k], lcount[k]);
    }
    __syncthreads();

    for (int i = tid; i < cnt; i += 256) {
        int r = rows[eb0 + i];
        int b = r >> ROW_SHIFT;
        int p = atomicAdd(&lcursor[b], 1);
        sx[p] = ((r & (ROWS_PER_BUCKET - 1)) << COL_BITS) | cols[eb0 + i];
        sy[p] = __float_as_int(vals[eb0 + i]);
        sbk[p] = (unsigned short)b;
    }
    __syncthreads();

    for (int i = tid; i < cnt; i += 256) {
        int b = sbk[i];
        int dest = gbase[b] + (i - lstart[b]);
        packed[dest] = make_int2(sx[i], sy[i]);
    }
}

// 2 blocks per bucket (feature halves). In-LDS counting sort by local row,
// then register-accumulated gather: 8 row-lanes x 32 feature-lanes,
// 8-wide unrolled independent Y loads, coalesced out+= per row.
__global__ __launch_bounds__(256) void bucket_gather_split(
    const int* __restrict__ bstart, const int* __restrict__ bend,
    const int2* __restrict__ packed, const float* __restrict__ Y,
    float* __restrict__ out, int n_nodes) {
    __shared__ int2 sxy[MAXB];                     // 16 KB
    __shared__ unsigned short dsti[MAXB];          // 4 KB
    __shared__ int hist[ROWS_PER_BUCKET];
    __shared__ int chs[ROWS_PER_BUCKET];
    __shared__ int chc[ROWS_PER_BUCKET];

    int tid = threadIdx.x;
    int bucket = blockIdx.x >> 1;
    int fbase = (blockIdx.x & 1) * 32;
    int fgroup = tid & 31;
    int rowlane = tid >> 5;        // 0..7
    int s = bstart[bucket];
    int e = bend[bucket];
    int row0 = bucket * ROWS_PER_BUCKET;

    for (int cb = s; cb < e; cb += MAXB) {
        int cnt = min(MAXB, e - cb);

        if (tid < ROWS_PER_BUCKET) hist[tid] = 0;
        __syncthreads();

        for (int i = tid; i < cnt; i += 256) {
            int2 a = packed[cb + i];
            sxy[i] = a;
            atomicAdd(&hist[a.x >> COL_BITS], 1);
        }
        __syncthreads();

        if (tid < ROWS_PER_BUCKET) chs[tid] = hist[tid];
        __syncthreads();
#pragma unroll
        for (int o = 1; o < ROWS_PER_BUCKET; o <<= 1) {
            int t = 0;
            if (tid < ROWS_PER_BUCKET && tid >= o) t = chs[tid - o];
            __syncthreads();
            if (tid < ROWS_PER_BUCKET) chs[tid] += t;
            __syncthreads();
        }
        if (tid < ROWS_PER_BUCKET) {
            int excl = chs[tid] - hist[tid];
            chs[tid] = excl;
            chc[tid] = excl;
        }
        __syncthreads();

        for (int i = tid; i < cnt; i += 256) {
            int r = sxy[i].x >> COL_BITS;
            int p = atomicAdd(&chc[r], 1);
            dsti[p] = (unsigned short)i;
        }
        __syncthreads();

        for (int rr = 0; rr < 16; ++rr) {
            int r = rowlane * 16 + rr;
            int rc = hist[r];
            int node = row0 + r;
            if (rc == 0 || node >= n_nodes) continue;
            int rs = chs[r];
            float acc = 0.f;
            int j = 0;
            for (; j + 8 <= rc; j += 8) {
                int i0 = dsti[rs + j + 0], i1 = dsti[rs + j + 1];
                int i2 = dsti[rs + j + 2], i3 = dsti[rs + j + 3];
                int i4 = dsti[rs + j + 4], i5 = dsti[rs + j + 5];
                int i6 = dsti[rs + j + 6], i7 = dsti[rs + j + 7];
                int2 a0 = sxy[i0], a1 = sxy[i1], a2 = sxy[i2], a3 = sxy[i3];
                int2 a4 = sxy[i4], a5 = sxy[i5], a6 = sxy[i6], a7 = sxy[i7];
                float f0 = Y[(size_t)(a0.x & COL_MASK) * 64 + fbase + fgroup];
                float f1 = Y[(size_t)(a1.x & COL_MASK) * 64 + fbase + fgroup];
                float f2 = Y[(size_t)(a2.x & COL_MASK) * 64 + fbase + fgroup];
                float f3 = Y[(size_t)(a3.x & COL_MASK) * 64 + fbase + fgroup];
                float f4 = Y[(size_t)(a4.x & COL_MASK) * 64 + fbase + fgroup];
                float f5 = Y[(size_t)(a5.x & COL_MASK) * 64 + fbase + fgroup];
                float f6 = Y[(size_t)(a6.x & COL_MASK) * 64 + fbase + fgroup];
                float f7 = Y[(size_t)(a7.x & COL_MASK) * 64 + fbase + fgroup];
                acc = fmaf(__int_as_float(a0.y), f0, acc);
                acc = fmaf(__int_as_float(a1.y), f1, acc);
                acc = fmaf(__int_as_float(a2.y), f2, acc);
                acc = fmaf(__int_as_float(a3.y), f3, acc);
                acc = fmaf(__int_as_float(a4.y), f4, acc);
                acc = fmaf(__int_as_float(a5.y), f5, acc);
                acc = fmaf(__int_as_float(a6.y), f6, acc);
                acc = fmaf(__int_as_float(a7.y), f7, acc);
            }
            for (; j + 4 <= rc; j += 4) {
                int i0 = dsti[rs + j + 0], i1 = dsti[rs + j + 1];
                int i2 = dsti[rs + j + 2], i3 = dsti[rs + j + 3];
                int2 a0 = sxy[i0], a1 = sxy[i1], a2 = sxy[i2], a3 = sxy[i3];
                float f0 = Y[(size_t)(a0.x & COL_MASK) * 64 + fbase + fgroup];
                float f1 = Y[(size_t)(a1.x & COL_MASK) * 64 + fbase + fgroup];
                float f2 = Y[(size_t)(a2.x & COL_MASK) * 64 + fbase + fgroup];
                float f3 = Y[(size_t)(a3.x & COL_MASK) * 64 + fbase + fgroup];
                acc = fmaf(__int_as_float(a0.y), f0, acc);
                acc = fmaf(__int_as_float(a1.y), f1, acc);
                acc = fmaf(__int_as_float(a2.y), f2, acc);
                acc = fmaf(__int_as_float(a3.y), f3, acc);
            }
            for (; j < rc; ++j) {
                int i0 = dsti[rs + j];
                int2 a0 = sxy[i0];
                acc = fmaf(__int_as_float(a0.y),
                           Y[(size_t)(a0.x & COL_MASK) * 64 + fbase + fgroup], acc);
            }
            out[(size_t)node * 64 + fbase + fgroup] += acc;   // out holds Z
        }
        __syncthreads();
    }
}

// ---------------- fallback (atomic path) ----------------

__global__ __launch_bounds__(256) void edge_scatter(
    const int* __restrict__ rows, const int* __restrict__ cols,
    const float* __restrict__ vals, const float* __restrict__ Y,
    float* __restrict__ out, int n_edges)
{
    int t = blockIdx.x * 256 + threadIdx.x;
    int e = t >> 4;
    int f = (t & 15) << 2;
    if (e >= n_edges) return;
    int r = rows[e];
    int c = cols[e];
    float v = vals[e];
    float4 y = *(const float4*)(Y + (size_t)c * 64 + f);
    float* o = out + (size_t)r * 64 + f;
    atomicAdd(o + 0, v * y.x);
    atomicAdd(o + 1, v * y.y);
    atomicAdd(o + 2, v * y.z);
    atomicAdd(o + 3, v * y.w);
}

extern "C" void kernel_launch(void* const* d_in, const int* in_sizes, int n_in,
                              void* d_out, int out_size, void* d_ws, size_t ws_size,
                              hipStream_t stream) {
    const int*   rows = (const int*)d_in[0];
    const int*   cols = (const int*)d_in[1];
    const float* vals = (const float*)d_in[2];
    const float* X    = (const float*)d_in[3];
    const float* W1   = (const float*)d_in[4];
    const float* b1   = (const float*)d_in[5];
    const float* W2   = (const float*)d_in[6];
    const float* b2   = (const float*)d_in[7];
    float* out = (float*)d_out;

    const int n_edges = in_sizes[0];
    const int n_nodes = in_sizes[3] / 64;
    const int nbuck = (n_nodes + ROWS_PER_BUCKET - 1) / ROWS_PER_BUCKET;

    char* ws = (char*)d_ws;
    size_t o_Y      = 0;
    size_t o_gcount = o_Y + (size_t)n_nodes * 64 * 4;
    size_t o_bstart = o_gcount + NBUCK_PAD * 4;
    size_t o_gcurs  = o_bstart + NBUCK_PAD * 4;
    size_t o_packed = o_gcurs + NBUCK_PAD * 4;
    size_t need     = o_packed + (size_t)n_edges * 8;

    float* Y = (float*)(ws + o_Y);

    int nblocks = (n_nodes + 127) / 128;
    node_transform<<<nblocks, 256, 0, stream>>>(X, W1, b1, W2, b2, Y, out, n_nodes);

    if (ws_size >= need && nbuck <= NBUCK_PAD && nbuck <= 1024 &&
        n_nodes <= (1 << COL_BITS)) {
        int*  gcount = (int*)(ws + o_gcount);
        int*  bstart = (int*)(ws + o_bstart);
        int*  gcursor= (int*)(ws + o_gcurs);
        int2* packed = (int2*)(ws + o_packed);

        int eb = (n_edges + CHUNK - 1) / CHUNK;

        zero_counts<<<(NBUCK_PAD + 255) / 256, 256, 0, stream>>>(gcount, NBUCK_PAD);
        bucket_hist<<<eb, 256, 0, stream>>>(rows, gcount, n_edges, nbuck);
        scan_buckets<<<1, 1024, 0, stream>>>(gcount, bstart, gcursor, nbuck);
        bin_scatter<<<eb, 256, 0, stream>>>(rows, cols, vals, gcursor, packed, n_edges);
        bucket_gather_split<<<nbuck * 2, 256, 0, stream>>>(bstart, gcursor, packed, Y, out, n_nodes);
    } else {
        long long threads = (long long)n_edges * 16;
        int eblocks = (int)((threads + 255) / 256);
        edge_scatter<<<eblocks, 256, 0, stream>>>(rows, cols, vals, Y, out, n_edges);
    }
}

// Round 7
// 214.290 us; speedup vs baseline: 3.3461x; 1.0685x over previous
//
#include <hip/hip_runtime.h>

// out = L@(X@W1 + X^2@W2) + X@W1 + b1 + b2
// Y (bf16, ws) = X@W1 + X^2@W2 ; Z = X@W1 + b1 + b2 (node_transform -> out).
// Fixed-capacity 128-row buckets (CAP=2048, +13 sigma above mean 1536):
//   cursor_init -> bin_scatter (LDS chunk-sort, coalesced runs, overflow
//   append if a bucket ever exceeds CAP) -> bucket_gather_split (2 blocks
//   per bucket, feature halves, in-LDS counting sort + register gather)
//   -> overflow_scatter (empty in practice). No global output atomics.

#define ROWS_PER_BUCKET 128
#define ROW_SHIFT 7
#define NBUCK_PAD 784        // 196*4, covers nbuck=782
#define SCAN_T 196
#define CAP 2048             // per-bucket fixed capacity
#define CHUNK 4096           // edges per bin_scatter block
#define MAXB 2048            // max bucket-chunk held in LDS by gather
#define COL_BITS 17
#define COL_MASK 0x1FFFF
#define OVF_CAP 65536

__device__ __forceinline__ unsigned short f2bf(float x) {
    unsigned u = __float_as_uint(x);
    unsigned r = (u + 0x7FFFu + ((u >> 16) & 1u)) >> 16;   // RNE
    return (unsigned short)r;
}
__device__ __forceinline__ float bf2f(unsigned short h) {
    return __uint_as_float(((unsigned)h) << 16);
}

__global__ __launch_bounds__(256) void node_transform(
    const float* __restrict__ X, const float* __restrict__ W1,
    const float* __restrict__ b1, const float* __restrict__ W2,
    const float* __restrict__ b2, unsigned short* __restrict__ Yb,
    float* __restrict__ Z, int n_nodes)
{
    __shared__ float W1s[64 * 64];
    __shared__ float W2s[64 * 64];
    __shared__ float xs[128][65];
    __shared__ float bs[64];

    const int tid = threadIdx.x;
    const int base = blockIdx.x * 128;

    {
        const float4* w1v = (const float4*)W1;
        const float4* w2v = (const float4*)W2;
        float4* s1 = (float4*)W1s;
        float4* s2 = (float4*)W2s;
#pragma unroll
        for (int i = 0; i < 4; ++i) {
            s1[tid + 256 * i] = w1v[tid + 256 * i];
            s2[tid + 256 * i] = w2v[tid + 256 * i];
        }
    }
    if (tid < 64) bs[tid] = b1[tid] + b2[tid];

    {
#pragma unroll
        for (int i = 0; i < 8; ++i) {
            int idx = (tid + 256 * i) * 4;
            int r = idx >> 6, c = idx & 63;
            if (base + r < n_nodes) {
                float4 v = *(const float4*)(X + (size_t)base * 64 + idx);
                xs[r][c + 0] = v.x; xs[r][c + 1] = v.y;
                xs[r][c + 2] = v.z; xs[r][c + 3] = v.w;
            }
        }
    }
    __syncthreads();

    const int tx = tid & 7;
    const int ty = tid >> 3;

    float acc1[4][8] = {};
    float acc2[4][8] = {};

#pragma unroll 2
    for (int k = 0; k < 64; ++k) {
        float4 wa0 = *(const float4*)(W1s + k * 64 + tx * 8);
        float4 wa1 = *(const float4*)(W1s + k * 64 + tx * 8 + 4);
        float4 wb0 = *(const float4*)(W2s + k * 64 + tx * 8);
        float4 wb1 = *(const float4*)(W2s + k * 64 + tx * 8 + 4);
#pragma unroll
        for (int i = 0; i < 4; ++i) {
            float xv = xs[ty * 4 + i][k];
            float xq = xv * xv;
            acc1[i][0] = fmaf(xv, wa0.x, acc1[i][0]);
            acc1[i][1] = fmaf(xv, wa0.y, acc1[i][1]);
            acc1[i][2] = fmaf(xv, wa0.z, acc1[i][2]);
            acc1[i][3] = fmaf(xv, wa0.w, acc1[i][3]);
            acc1[i][4] = fmaf(xv, wa1.x, acc1[i][4]);
            acc1[i][5] = fmaf(xv, wa1.y, acc1[i][5]);
            acc1[i][6] = fmaf(xv, wa1.z, acc1[i][6]);
            acc1[i][7] = fmaf(xv, wa1.w, acc1[i][7]);
            acc2[i][0] = fmaf(xq, wb0.x, acc2[i][0]);
            acc2[i][1] = fmaf(xq, wb0.y, acc2[i][1]);
            acc2[i][2] = fmaf(xq, wb0.z, acc2[i][2]);
            acc2[i][3] = fmaf(xq, wb0.w, acc2[i][3]);
            acc2[i][4] = fmaf(xq, wb1.x, acc2[i][4]);
            acc2[i][5] = fmaf(xq, wb1.y, acc2[i][5]);
            acc2[i][6] = fmaf(xq, wb1.z, acc2[i][6]);
            acc2[i][7] = fmaf(xq, wb1.w, acc2[i][7]);
        }
    }

    float bv[8];
#pragma unroll
    for (int j = 0; j < 8; ++j) bv[j] = bs[tx * 8 + j];

#pragma unroll
    for (int i = 0; i < 4; ++i) {
        int node = base + ty * 4 + i;
        if (node < n_nodes) {
            float z[8];
            unsigned pk[4];
#pragma unroll
            for (int j = 0; j < 4; ++j) {
                float ylo = acc1[i][2 * j]     + acc2[i][2 * j];
                float yhi = acc1[i][2 * j + 1] + acc2[i][2 * j + 1];
                pk[j] = (unsigned)f2bf(ylo) | ((unsigned)f2bf(yhi) << 16);
            }
#pragma unroll
            for (int j = 0; j < 8; ++j) z[j] = acc1[i][j] + bv[j];
            unsigned short* yp = Yb + (size_t)node * 64 + tx * 8;
            float* zp = Z + (size_t)node * 64 + tx * 8;
            *(uint4*)(yp) = make_uint4(pk[0], pk[1], pk[2], pk[3]);
            *(float4*)(zp)     = make_float4(z[0], z[1], z[2], z[3]);
            *(float4*)(zp + 4) = make_float4(z[4], z[5], z[6], z[7]);
        }
    }
}

// ---------------- fixed-capacity bucket build ----------------

__global__ __launch_bounds__(256) void cursor_init(
    int* __restrict__ gcursor, int* __restrict__ ovf_count, int nbp) {
    int i = blockIdx.x * 256 + threadIdx.x;
    if (i < nbp) gcursor[i] = i * CAP;
    if (i == 0) *ovf_count = 0;
}

// LDS-staged binned scatter with fixed-capacity buckets + overflow append.
__global__ __launch_bounds__(256) void bin_scatter(
    const int* __restrict__ rows, const int* __restrict__ cols,
    const float* __restrict__ vals, int* __restrict__ gcursor,
    int2* __restrict__ packed, int* __restrict__ ovf_count,
    int4* __restrict__ ovf, int n_edges) {
    __shared__ int lcount[NBUCK_PAD];
    __shared__ int lstart[NBUCK_PAD];
    __shared__ int lcursor[NBUCK_PAD];
    __shared__ int gbase[NBUCK_PAD];
    __shared__ int sx[CHUNK];
    __shared__ int sy[CHUNK];
    __shared__ unsigned short sbk[CHUNK];

    int tid = threadIdx.x;
    int eb0 = blockIdx.x * CHUNK;
    int cnt = min(CHUNK, n_edges - eb0);

    for (int k = tid; k < NBUCK_PAD; k += 256) lcount[k] = 0;
    __syncthreads();

    for (int i = tid; i < cnt; i += 256)
        atomicAdd(&lcount[rows[eb0 + i] >> ROW_SHIFT], 1);
    __syncthreads();

    // exclusive scan of lcount[0..NBUCK_PAD): thread t<SCAN_T owns 4t..4t+3
    int c0 = 0, c1 = 0, c2 = 0, c3 = 0, psum = 0;
    if (tid < SCAN_T) {
        c0 = lcount[tid * 4 + 0]; c1 = lcount[tid * 4 + 1];
        c2 = lcount[tid * 4 + 2]; c3 = lcount[tid * 4 + 3];
        psum = c0 + c1 + c2 + c3;
    }
    sx[tid] = psum;
    __syncthreads();
#pragma unroll
    for (int o = 1; o < 256; o <<= 1) {
        int t = (tid >= o) ? sx[tid - o] : 0;
        __syncthreads();
        sx[tid] += t;
        __syncthreads();
    }
    int base0 = sx[tid] - psum;
    __syncthreads();
    if (tid < SCAN_T) {
        lstart[tid * 4 + 0] = base0;
        lstart[tid * 4 + 1] = base0 + c0;
        lstart[tid * 4 + 2] = base0 + c0 + c1;
        lstart[tid * 4 + 3] = base0 + c0 + c1 + c2;
    }
    __syncthreads();

    for (int k = tid; k < NBUCK_PAD; k += 256) {
        lcursor[k] = lstart[k];
        if (lcount[k] > 0) gbase[k] = atomicAdd(&gcursor[k], lcount[k]);
    }
    __syncthreads();

    for (int i = tid; i < cnt; i += 256) {
        int r = rows[eb0 + i];
        int b = r >> ROW_SHIFT;
        int p = atomicAdd(&lcursor[b], 1);
        sx[p] = ((r & (ROWS_PER_BUCKET - 1)) << COL_BITS) | cols[eb0 + i];
        sy[p] = __float_as_int(vals[eb0 + i]);
        sbk[p] = (unsigned short)b;
    }
    __syncthreads();

    for (int i = tid; i < cnt; i += 256) {
        int b = sbk[i];
        int dest = gbase[b] + (i - lstart[b]);
        if (dest < (b + 1) * CAP) {
            packed[dest] = make_int2(sx[i], sy[i]);
        } else {
            int p = atomicAdd(ovf_count, 1);
            if (p < OVF_CAP)
                ovf[p] = make_int4(b * ROWS_PER_BUCKET + (sx[i] >> COL_BITS),
                                   sx[i] & COL_MASK, sy[i], 0);
        }
    }
}

// 2 blocks per bucket (feature halves). In-LDS counting sort by local row,
// then register-accumulated gather from bf16 Y, coalesced out+= per row.
__global__ __launch_bounds__(256) void bucket_gather_split(
    const int* __restrict__ gcursor, const int2* __restrict__ packed,
    const unsigned short* __restrict__ Yb, float* __restrict__ out,
    int n_nodes) {
    __shared__ int2 sxy[MAXB];                     // 16 KB
    __shared__ unsigned short dsti[MAXB];          // 4 KB
    __shared__ int hist[ROWS_PER_BUCKET];
    __shared__ int chs[ROWS_PER_BUCKET];
    __shared__ int chc[ROWS_PER_BUCKET];

    int tid = threadIdx.x;
    int bucket = blockIdx.x >> 1;
    int fcol = ((blockIdx.x & 1) * 32) + (tid & 31);
    int rowlane = tid >> 5;        // 0..7
    int s = bucket * CAP;
    int e = min(gcursor[bucket], s + CAP);
    int row0 = bucket * ROWS_PER_BUCKET;

    for (int cb = s; cb < e; cb += MAXB) {
        int cnt = min(MAXB, e - cb);

        if (tid < ROWS_PER_BUCKET) hist[tid] = 0;
        __syncthreads();

        for (int i = tid; i < cnt; i += 256) {
            int2 a = packed[cb + i];
            sxy[i] = a;
            atomicAdd(&hist[a.x >> COL_BITS], 1);
        }
        __syncthreads();

        if (tid < ROWS_PER_BUCKET) chs[tid] = hist[tid];
        __syncthreads();
#pragma unroll
        for (int o = 1; o < ROWS_PER_BUCKET; o <<= 1) {
            int t = 0;
            if (tid < ROWS_PER_BUCKET && tid >= o) t = chs[tid - o];
            __syncthreads();
            if (tid < ROWS_PER_BUCKET) chs[tid] += t;
            __syncthreads();
        }
        if (tid < ROWS_PER_BUCKET) {
            int excl = chs[tid] - hist[tid];
            chs[tid] = excl;
            chc[tid] = excl;
        }
        __syncthreads();

        for (int i = tid; i < cnt; i += 256) {
            int r = sxy[i].x >> COL_BITS;
            int p = atomicAdd(&chc[r], 1);
            dsti[p] = (unsigned short)i;
        }
        __syncthreads();

        for (int rr = 0; rr < 16; ++rr) {
            int r = rowlane * 16 + rr;
            int rc = hist[r];
            int node = row0 + r;
            if (rc == 0 || node >= n_nodes) continue;
            int rs = chs[r];
            float acc = 0.f;
            int j = 0;
            for (; j + 8 <= rc; j += 8) {
                int i0 = dsti[rs + j + 0], i1 = dsti[rs + j + 1];
                int i2 = dsti[rs + j + 2], i3 = dsti[rs + j + 3];
                int i4 = dsti[rs + j + 4], i5 = dsti[rs + j + 5];
                int i6 = dsti[rs + j + 6], i7 = dsti[rs + j + 7];
                int2 a0 = sxy[i0], a1 = sxy[i1], a2 = sxy[i2], a3 = sxy[i3];
                int2 a4 = sxy[i4], a5 = sxy[i5], a6 = sxy[i6], a7 = sxy[i7];
                float f0 = bf2f(Yb[(size_t)(a0.x & COL_MASK) * 64 + fcol]);
                float f1 = bf2f(Yb[(size_t)(a1.x & COL_MASK) * 64 + fcol]);
                float f2 = bf2f(Yb[(size_t)(a2.x & COL_MASK) * 64 + fcol]);
                float f3 = bf2f(Yb[(size_t)(a3.x & COL_MASK) * 64 + fcol]);
                float f4 = bf2f(Yb[(size_t)(a4.x & COL_MASK) * 64 + fcol]);
                float f5 = bf2f(Yb[(size_t)(a5.x & COL_MASK) * 64 + fcol]);
                float f6 = bf2f(Yb[(size_t)(a6.x & COL_MASK) * 64 + fcol]);
                float f7 = bf2f(Yb[(size_t)(a7.x & COL_MASK) * 64 + fcol]);
                acc = fmaf(__int_as_float(a0.y), f0, acc);
                acc = fmaf(__int_as_float(a1.y), f1, acc);
                acc = fmaf(__int_as_float(a2.y), f2, acc);
                acc = fmaf(__int_as_float(a3.y), f3, acc);
                acc = fmaf(__int_as_float(a4.y), f4, acc);
                acc = fmaf(__int_as_float(a5.y), f5, acc);
                acc = fmaf(__int_as_float(a6.y), f6, acc);
                acc = fmaf(__int_as_float(a7.y), f7, acc);
            }
            for (; j + 4 <= rc; j += 4) {
                int i0 = dsti[rs + j + 0], i1 = dsti[rs + j + 1];
                int i2 = dsti[rs + j + 2], i3 = dsti[rs + j + 3];
                int2 a0 = sxy[i0], a1 = sxy[i1], a2 = sxy[i2], a3 = sxy[i3];
                float f0 = bf2f(Yb[(size_t)(a0.x & COL_MASK) * 64 + fcol]);
                float f1 = bf2f(Yb[(size_t)(a1.x & COL_MASK) * 64 + fcol]);
                float f2 = bf2f(Yb[(size_t)(a2.x & COL_MASK) * 64 + fcol]);
                float f3 = bf2f(Yb[(size_t)(a3.x & COL_MASK) * 64 + fcol]);
                acc = fmaf(__int_as_float(a0.y), f0, acc);
                acc = fmaf(__int_as_float(a1.y), f1, acc);
                acc = fmaf(__int_as_float(a2.y), f2, acc);
                acc = fmaf(__int_as_float(a3.y), f3, acc);
            }
            for (; j < rc; ++j) {
                int i0 = dsti[rs + j];
                int2 a0 = sxy[i0];
                acc = fmaf(__int_as_float(a0.y),
                           bf2f(Yb[(size_t)(a0.x & COL_MASK) * 64 + fcol]), acc);
            }
            out[(size_t)node * 64 + fcol] += acc;   // out holds Z
        }
        __syncthreads();
    }
}

// drains the (normally empty) overflow list with global atomics
__global__ __launch_bounds__(256) void overflow_scatter(
    const int* __restrict__ ovf_count, const int4* __restrict__ ovf,
    const unsigned short* __restrict__ Yb, float* __restrict__ out) {
    int cnt = min(*ovf_count, OVF_CAP);
    long long total = (long long)cnt * 64;
    for (long long i = blockIdx.x * 256 + threadIdx.x; i < total;
         i += (long long)gridDim.x * 256) {
        int e = (int)(i >> 6), f = (int)(i & 63);
        int4 a = ovf[e];
        atomicAdd(&out[(size_t)a.x * 64 + f],
                  __int_as_float(a.z) * bf2f(Yb[(size_t)a.y * 64 + f]));
    }
}

// ---------------- fallback (atomic path) ----------------

__global__ __launch_bounds__(256) void edge_scatter(
    const int* __restrict__ rows, const int* __restrict__ cols,
    const float* __restrict__ vals, const unsigned short* __restrict__ Yb,
    float* __restrict__ out, int n_edges)
{
    int t = blockIdx.x * 256 + threadIdx.x;
    int e = t >> 4;
    int f = (t & 15) << 2;
    if (e >= n_edges) return;
    int r = rows[e];
    int c = cols[e];
    float v = vals[e];
    const unsigned short* y = Yb + (size_t)c * 64 + f;
    float* o = out + (size_t)r * 64 + f;
    atomicAdd(o + 0, v * bf2f(y[0]));
    atomicAdd(o + 1, v * bf2f(y[1]));
    atomicAdd(o + 2, v * bf2f(y[2]));
    atomicAdd(o + 3, v * bf2f(y[3]));
}

extern "C" void kernel_launch(void* const* d_in, const int* in_sizes, int n_in,
                              void* d_out, int out_size, void* d_ws, size_t ws_size,
                              hipStream_t stream) {
    const int*   rows = (const int*)d_in[0];
    const int*   cols = (const int*)d_in[1];
    const float* vals = (const float*)d_in[2];
    const float* X    = (const float*)d_in[3];
    const float* W1   = (const float*)d_in[4];
    const float* b1   = (const float*)d_in[5];
    const float* W2   = (const float*)d_in[6];
    const float* b2   = (const float*)d_in[7];
    float* out = (float*)d_out;

    const int n_edges = in_sizes[0];
    const int n_nodes = in_sizes[3] / 64;
    const int nbuck = (n_nodes + ROWS_PER_BUCKET - 1) / ROWS_PER_BUCKET;

    char* ws = (char*)d_ws;
    size_t o_Yb     = 0;                                    // bf16 Y
    size_t o_packed = o_Yb + (size_t)n_nodes * 64 * 2;      // 16B-aligned (n*128)
    size_t o_ovf    = o_packed + (size_t)NBUCK_PAD * CAP * 8;
    size_t o_gcurs  = o_ovf + (size_t)OVF_CAP * 16;
    size_t o_ovfcnt = o_gcurs + NBUCK_PAD * 4;
    size_t need     = o_ovfcnt + 16;

    unsigned short* Yb = (unsigned short*)(ws + o_Yb);

    int nblocks = (n_nodes + 127) / 128;
    node_transform<<<nblocks, 256, 0, stream>>>(X, W1, b1, W2, b2, Yb, out, n_nodes);

    if (ws_size >= need && nbuck <= NBUCK_PAD && n_nodes <= (1 << COL_BITS)) {
        int2* packed  = (int2*)(ws + o_packed);
        int4* ovf     = (int4*)(ws + o_ovf);
        int*  gcursor = (int*)(ws + o_gcurs);
        int*  ovfcnt  = (int*)(ws + o_ovfcnt);

        int eb = (n_edges + CHUNK - 1) / CHUNK;

        cursor_init<<<(NBUCK_PAD + 255) / 256, 256, 0, stream>>>(gcursor, ovfcnt, NBUCK_PAD);
        bin_scatter<<<eb, 256, 0, stream>>>(rows, cols, vals, gcursor, packed,
                                            ovfcnt, ovf, n_edges);
        bucket_gather_split<<<nbuck * 2, 256, 0, stream>>>(gcursor, packed, Yb, out, n_nodes);
        overflow_scatter<<<128, 256, 0, stream>>>(ovfcnt, ovf, Yb, out);
    } else {
        long long threads = (long long)n_edges * 16;
        int eblocks = (int)((threads + 255) / 256);
        edge_scatter<<<eblocks, 256, 0, stream>>>(rows, cols, vals, Yb, out, n_edges);
    }
}